// Round 4
// baseline (518.402 us; speedup 1.0000x reference)
//
#include <hip/hip_runtime.h>
#include <hip/hip_bf16.h>

// KeySelect2 round 4:
// - convm: block 256 / grid (128,4) -> 512 blocks = 2 blocks/CU; A-frags in a
//   single loop-carried afr[2][9] (72 VGPR) reloaded at iteration end for kb+1.
//   Round-3 bug: VGPR=68 proved the compiler reloaded A inside the tap loop.
// - localw: grid (64,8) = 512 blocks (4-row h-groups), acc[4ch][4h].
// - wprep: LDS transpose (round-3 version had 9x read amplification).

#define B_ 4
#define CM_ 128

typedef __attribute__((ext_vector_type(8))) short short8;
typedef __attribute__((ext_vector_type(4))) float floatx4;
typedef __attribute__((address_space(3))) unsigned lds_as;
typedef __attribute__((address_space(1))) const unsigned glb_as;

__device__ inline short f2bf(float f) {
  union { float f; unsigned u; } v; v.f = f;
  unsigned r = v.u + 0x7fff + ((v.u >> 16) & 1);  // RNE
  return (short)(r >> 16);
}
__device__ inline float bf2f(unsigned short u) {
  union { unsigned u; float f; } v; v.u = ((unsigned)u) << 16;
  return v.f;
}

// ---- weight prepack: [oc][ic][3][3] -> [kb][tap][oc][32] bf16, LDS transpose
// grid (cin/32, 2): block = one kb x 64 ocs. Coalesced read, coalesced write.
__global__ void wprep_kernel(const float* __restrict__ w, short* __restrict__ wpk,
                             int cin) {
  __shared__ unsigned short lw[18432];  // [tap][oc64][ic32]
  int kb = blockIdx.x, oc0 = blockIdx.y * 64;
  int tid = threadIdx.x;
  for (int e = tid; e < 64 * 288; e += 256) {
    int oc = e / 288, r = e % 288;
    int ic = r / 9, tap = r % 9;
    lw[tap * 2048 + oc * 32 + ic] =
        (unsigned short)f2bf(w[((size_t)(oc0 + oc) * cin + kb * 32 + ic) * 9 + tap]);
  }
  __syncthreads();
  for (int f = tid; f < 18432; f += 256) {
    int tap = f / 2048, rem = f % 2048;  // rem = oc*32 + icb
    wpk[(size_t)kb * 36864 + tap * 4096 + oc0 * 32 + rem] = (short)lw[f];
  }
}

// ---- x prepack: NCHW fp32 -> [b][kb][row][col][unit^sw][8] bf16 ------------
template <int KB>
__global__ void xprep_kernel(const float* __restrict__ x, short* __restrict__ xt) {
  int kb = blockIdx.x >> 4, rg = blockIdx.x & 15;
  int b = blockIdx.y;
  int row = rg * 4 + (threadIdx.x >> 6);
  int col = threadIdx.x & 63;
  const float* xs = x + (((size_t)b * (KB * 32) + kb * 32) * 64 + row) * 64 + col;
  short* xd = xt + ((((size_t)b * KB + kb) * 64 + row) * 64 + col) * 32;
  int sw = (col >> 1) & 3;
#pragma unroll
  for (int u = 0; u < 4; u++) {
    short8 pk;
#pragma unroll
    for (int j = 0; j < 8; j++) pk[j] = f2bf(xs[(size_t)(u * 8 + j) * 4096]);
    *(short8*)(xd + (u ^ sw) * 8) = pk;
  }
}

// ---- MFMA conv -------------------------------------------------------------
// grid (128, 4); block 256 (4 waves). blockIdx.y = oc quarter (32 ocs).
// wave: ng = wv&1 (row of pair), ch = wv>>1 (col half, 2 tiles of 16).
// Per wave per kb: 18 A-loads (global, L2), 18 ds_read_b128, 36 MFMA.
template <int KB>
__global__ __launch_bounds__(256, 2)
void convm_kernel(const short* __restrict__ xt, const short* __restrict__ wpk,
                  float* __restrict__ y) {
  __shared__ __attribute__((aligned(16))) short lx[16896];  // 2 x (4 rows x 66 cols x 32)
  int tid = threadIdx.x;
  int lane = tid & 63;
  int wv = tid >> 6;
  int n16 = lane & 15, quad = lane >> 4;
  int pb = blockIdx.x;
  int b = pb >> 5, h0 = (pb & 31) * 2;
  int oc0 = blockIdx.y * 32;
  int ng = wv & 1;
  int ch = wv >> 1;

  // zero pad columns (j=0, j=65) of every row, both buffers
  {
    int reg = tid >> 4, dw = tid & 15;
    int bu = reg >> 3, rr = (reg >> 1) & 3, cl = reg & 1;
    *(int*)(lx + bu * 8448 + rr * 2112 + (cl ? 65 : 0) * 32 + dw * 2) = 0;
  }
  // zero out-of-range boundary rows (never DMA'd)
  if (h0 == 0)
    for (int i = tid; i < 2112; i += 256) {
      int bu = i >= 1056; int o = i - bu * 1056;
      *((int*)lx + bu * 4224 + o) = 0;
    }
  if (h0 == 62)
    for (int i = tid; i < 2112; i += 256) {
      int bu = i >= 1056; int o = i - bu * 1056;
      *((int*)lx + bu * 4224 + 3 * 1056 + o) = 0;
    }

  // DMA one K-block slab: wave wv loads row h0-1+wv, 4 chunks of 1KB
  auto dma = [&](int kb, int buf) {
    int row = h0 - 1 + wv;
    if (row >= 0 && row < 64) {
#pragma unroll
      for (int t = 0; t < 4; t++) {
        const short* src =
            xt + ((((size_t)b * KB + kb) * 64 + row) * 64 + t * 16) * 32 + lane * 8;
        short* dst = lx + buf * 8448 + wv * 2112 + (1 + t * 16) * 32 + lane * 8;
        __builtin_amdgcn_global_load_lds((glb_as*)src, (lds_as*)dst, 16, 0, 0);
      }
    }
  };

  const short* wb0 = wpk + (size_t)(oc0 + n16) * 32 + quad * 8;
  const short* wb1 = wb0 + 512;  // +16 ocs

  short8 afr[2][9];
#pragma unroll
  for (int t = 0; t < 9; t++) {
    afr[0][t] = *(const short8*)(wb0 + t * 4096);
    afr[1][t] = *(const short8*)(wb1 + t * 4096);
  }
  dma(0, 0);

  floatx4 acc[2][2];
#pragma unroll
  for (int i = 0; i < 2; i++)
#pragma unroll
    for (int t2 = 0; t2 < 2; t2++) acc[i][t2] = (floatx4){0.f, 0.f, 0.f, 0.f};

  for (int kb = 0; kb < KB; kb++) {
    __syncthreads();  // drains DMA for kb
    if (kb + 1 < KB) dma(kb + 1, (kb + 1) & 1);
    const short* lb = lx + (kb & 1) * 8448;
#pragma unroll
    for (int tap = 0; tap < 9; tap++) {
      int r = tap / 3, s = tap % 3;
      const short* lr = lb + (ng + r) * 2112;
#pragma unroll
      for (int t2 = 0; t2 < 2; t2++) {
        int c = (ch * 2 + t2) * 16 + n16 + s - 1;  // source col, -1..64
        int uu = quad ^ ((c >> 1) & 3);
        short8 bf = *(const short8*)(lr + (c + 1) * 32 + uu * 8);
        acc[0][t2] = __builtin_amdgcn_mfma_f32_16x16x32_bf16(afr[0][tap], bf, acc[0][t2], 0, 0, 0);
        acc[1][t2] = __builtin_amdgcn_mfma_f32_16x16x32_bf16(afr[1][tap], bf, acc[1][t2], 0, 0, 0);
      }
    }
    // reload A for kb+1 (loop-carried; latency overlaps next barrier wait)
    if (kb + 1 < KB) {
      const short* wn0 = wb0 + (size_t)(kb + 1) * 36864;
      const short* wn1 = wb1 + (size_t)(kb + 1) * 36864;
#pragma unroll
      for (int t = 0; t < 9; t++) {
        afr[0][t] = *(const short8*)(wn0 + t * 4096);
        afr[1][t] = *(const short8*)(wn1 + t * 4096);
      }
    }
  }

  int row = h0 + ng;
#pragma unroll
  for (int i = 0; i < 2; i++)
#pragma unroll
    for (int t2 = 0; t2 < 2; t2++)
#pragma unroll
      for (int rg = 0; rg < 4; rg++) {
        int oc = oc0 + i * 16 + quad * 4 + rg;
        y[(((size_t)b * CM_ + oc) * 64 + row) * 64 + (ch * 2 + t2) * 16 + n16] = acc[i][t2][rg];
      }
}

// ---- BN stats --------------------------------------------------------------
__global__ void bnstats_kernel(const float* __restrict__ y, const float* __restrict__ g,
                               const float* __restrict__ bt, float2* __restrict__ scsh) {
  int c = blockIdx.x;
  int tid = threadIdx.x;
  float s = 0.f, s2 = 0.f;
  for (int b = 0; b < B_; b++) {
    const float4* p = (const float4*)(y + ((size_t)(b * CM_) + c) * 4096);
    for (int i = tid; i < 1024; i += 256) {
      float4 v = p[i];
      s += v.x + v.y + v.z + v.w;
      s2 += v.x * v.x + v.y * v.y + v.z * v.z + v.w * v.w;
    }
  }
  for (int off = 32; off > 0; off >>= 1) {
    s += __shfl_down(s, off);
    s2 += __shfl_down(s2, off);
  }
  __shared__ float rs[4], rq[4];
  if ((tid & 63) == 0) { rs[tid >> 6] = s; rq[tid >> 6] = s2; }
  __syncthreads();
  if (tid == 0) {
    float S = rs[0] + rs[1] + rs[2] + rs[3];
    float Q = rq[0] + rq[1] + rq[2] + rq[3];
    float mean = S * (1.f / 16384.f);
    float var = Q * (1.f / 16384.f) - mean * mean;
    float sc = g[c] * rsqrtf(var + 1e-5f);
    scsh[c] = make_float2(sc, bt[c] - mean * sc);
  }
}

// ---- atten transpose: [b,pix,81] -> att_t [b,81,pix] -----------------------
__global__ void attprep_kernel(const float* __restrict__ atten, float* __restrict__ att_t) {
  __shared__ float tile[5184];
  int b = blockIdx.x >> 6;
  int p0 = (blockIdx.x & 63) * 64;
  const float* src = atten + ((size_t)b * 4096 + p0) * 81;
  for (int e = threadIdx.x; e < 5184; e += 256) tile[e] = src[e];
  __syncthreads();
  for (int f = threadIdx.x; f < 5184; f += 256) {
    int k = f >> 6, w_ = f & 63;
    att_t[((size_t)b * 81 + k) * 4096 + p0 + w_] = tile[w_ * 81 + k];
  }
}

// ---- local weighting + subtract -> xt5 (bf16, conv5 layout) ----------------
// grid (64: b*16+hg (4 rows), 8: cgroup); block 256 (4 waves, 4 ch each).
__global__ __launch_bounds__(256, 2)
void localw_kernel(const float* __restrict__ y1, const float2* __restrict__ scsh1,
                   const float* __restrict__ y4, const float2* __restrict__ scsh4,
                   const float* __restrict__ att_t, short* __restrict__ xt5) {
  __shared__ unsigned short lkb[16][12][72];  // [ch][srcrow][col+4] bf16, 27.6 KB
  int bx = blockIdx.x;
  int b = bx >> 4, h0 = (bx & 15) * 4;
  int cg = blockIdx.y;
  int tid = threadIdx.x;
  int lane = tid & 63;
  int wv = tid >> 6;

  for (int e = tid; e < 16 * 12 * 72; e += 256) {
    int c_l = e / (12 * 72);
    int rem = e % (12 * 72);
    int gri = rem / 72, j = rem % 72;
    int row = h0 - 4 + gri, col = j - 4;
    float v = 0.f;
    if (row >= 0 && row < 64 && col >= 0 && col < 64) {
      float2 ss = scsh1[cg * 16 + c_l];
      v = fmaxf(0.f, y1[((size_t)(b * CM_) + cg * 16 + c_l) * 4096 + row * 64 + col] * ss.x + ss.y);
    }
    lkb[c_l][gri][j] = (unsigned short)f2bf(v);
  }
  __syncthreads();

  float acc[4][4];
#pragma unroll
  for (int cc = 0; cc < 4; cc++)
#pragma unroll
    for (int h_i = 0; h_i < 4; h_i++) acc[cc][h_i] = 0.f;

  const float* ab = att_t + (size_t)b * 81 * 4096 + h0 * 64 + lane;

#pragma unroll
  for (int gri = 0; gri < 12; ++gri) {
    float win[4][9];
#pragma unroll
    for (int cc = 0; cc < 4; ++cc)
#pragma unroll
      for (int dw = 0; dw < 9; ++dw)
        win[cc][dw] = bf2f(lkb[wv * 4 + cc][gri][lane + dw]);
#pragma unroll
    for (int h_i = 0; h_i < 4; ++h_i) {
      int r = gri - h_i;
      if (r < 0 || r > 8) continue;  // compile-time after unroll
      const float* ap = ab + (size_t)(r * 9) * 4096 + h_i * 64;
      float a[9];
#pragma unroll
      for (int dw = 0; dw < 9; ++dw) a[dw] = ap[(size_t)dw * 4096];
#pragma unroll
      for (int cc = 0; cc < 4; ++cc)
#pragma unroll
        for (int dw = 0; dw < 9; ++dw)
          acc[cc][h_i] = fmaf(a[dw], win[cc][dw], acc[cc][h_i]);
    }
  }

#pragma unroll
  for (int cc = 0; cc < 4; ++cc) {
    int c = cg * 16 + wv * 4 + cc;
    float2 ss4 = scsh4[c];
    int icb = c & 31;
    int uu = (icb >> 3) ^ ((lane >> 1) & 3);
#pragma unroll
    for (int h_i = 0; h_i < 4; ++h_i) {
      int h = h0 + h_i;
      size_t gi = ((size_t)(b * CM_) + c) * 4096 + h * 64 + lane;
      float lnk = fmaxf(0.f, y4[gi] * ss4.x + ss4.y);
      float dv = acc[cc][h_i] - lnk;
      xt5[((((size_t)b * 4 + (c >> 5)) * 64 + h) * 64 + lane) * 32 + uu * 8 + (icb & 7)] =
          f2bf(dv);
    }
  }
}

// ---- global avg pool with BN+ReLU ------------------------------------------
__global__ void pool_kernel(const float* __restrict__ y, const float2* __restrict__ scsh,
                            float* __restrict__ pooled) {
  int bc = blockIdx.x;
  int c = bc & 127;
  float2 ss = scsh[c];
  const float4* p = (const float4*)(y + (size_t)bc * 4096);
  float s = 0.f;
  for (int i = threadIdx.x; i < 1024; i += 256) {
    float4 v = p[i];
    s += fmaxf(0.f, v.x * ss.x + ss.y) + fmaxf(0.f, v.y * ss.x + ss.y) +
         fmaxf(0.f, v.z * ss.x + ss.y) + fmaxf(0.f, v.w * ss.x + ss.y);
  }
  for (int off = 32; off > 0; off >>= 1) s += __shfl_down(s, off);
  __shared__ float rs[4];
  if ((threadIdx.x & 63) == 0) rs[threadIdx.x >> 6] = s;
  __syncthreads();
  if (threadIdx.x == 0) pooled[bc] = (rs[0] + rs[1] + rs[2] + rs[3]) * (1.f / 4096.f);
}

// ---- fc1 + fc2 -------------------------------------------------------------
__global__ void fc_kernel(const float* __restrict__ pooled, const float* __restrict__ fc1w,
                          const float* __restrict__ fc1b, const float* __restrict__ fc2w,
                          const float* __restrict__ fc2b, float* __restrict__ out) {
  int lane = threadIdx.x;
  float p[B_][10];
#pragma unroll
  for (int b = 0; b < B_; b++)
#pragma unroll
    for (int j = 0; j < 10; j++) p[b][j] = 0.f;
  for (int c = lane; c < CM_; c += 64) {
#pragma unroll
    for (int b = 0; b < B_; b++) {
      float pv = pooled[b * CM_ + c];
#pragma unroll
      for (int j = 0; j < 10; j++) p[b][j] = fmaf(pv, fc1w[j * CM_ + c], p[b][j]);
    }
  }
  for (int off = 32; off > 0; off >>= 1)
#pragma unroll
    for (int b = 0; b < B_; b++)
#pragma unroll
      for (int j = 0; j < 10; j++) p[b][j] += __shfl_down(p[b][j], off);
  if (lane == 0) {
    for (int b = 0; b < B_; b++) {
      float o = fc2b[0];
      for (int j = 0; j < 10; j++) o += fc2w[j] * (p[b][j] + fc1b[j]);
      out[b] = o;
    }
  }
}

extern "C" void kernel_launch(void* const* d_in, const int* in_sizes, int n_in,
                              void* d_out, int out_size, void* d_ws, size_t ws_size,
                              hipStream_t stream) {
  const float* low_key    = (const float*)d_in[0];
  const float* low_nonkey = (const float*)d_in[1];
  const float* atten      = (const float*)d_in[2];
  const float* w1  = (const float*)d_in[3];
  const float* g1  = (const float*)d_in[4];
  const float* b1  = (const float*)d_in[5];
  const float* w4  = (const float*)d_in[6];
  const float* g4  = (const float*)d_in[7];
  const float* b4  = (const float*)d_in[8];
  const float* w5  = (const float*)d_in[9];
  const float* g5  = (const float*)d_in[10];
  const float* b5  = (const float*)d_in[11];
  const float* fc1w = (const float*)d_in[12];
  const float* fc1b = (const float*)d_in[13];
  const float* fc2w = (const float*)d_in[14];
  const float* fc2b = (const float*)d_in[15];

  char* w8 = (char*)d_ws;
  short* wpk = (short*)w8;                                   // 2,359,296 B (max)
  short* xt  = (short*)(w8 + 2359296);                       // 33,554,432 B
  short* xt5 = (short*)(w8 + 2359296 + 33554432);            // 4,194,304 B
  float* y1  = (float*)(w8 + 2359296 + 33554432 + 4194304);  // 8,388,608 B
  float* y4  = y1 + 2097152;                                 // 8,388,608 B
  float2* scsh1 = (float2*)(y4 + 2097152);
  float2* scsh4 = scsh1 + CM_;
  float2* scsh5 = scsh4 + CM_;
  float* pooled = (float*)(scsh5 + CM_);
  float* att_t = (float*)xt;  // aliases xt: xt dead after conv4's convm
  float* out = (float*)d_out;

  // conv1 path
  wprep_kernel<<<dim3(32, 2), 256, 0, stream>>>(w1, wpk, 1024);
  xprep_kernel<32><<<dim3(512, 4), 256, 0, stream>>>(low_key, xt);
  convm_kernel<32><<<dim3(128, 4), 256, 0, stream>>>(xt, wpk, y1);
  bnstats_kernel<<<128, 256, 0, stream>>>(y1, g1, b1, scsh1);

  // conv4 path (reuses wpk/xt — stream-ordered)
  wprep_kernel<<<dim3(32, 2), 256, 0, stream>>>(w4, wpk, 1024);
  xprep_kernel<32><<<dim3(512, 4), 256, 0, stream>>>(low_nonkey, xt);
  convm_kernel<32><<<dim3(128, 4), 256, 0, stream>>>(xt, wpk, y4);
  bnstats_kernel<<<128, 256, 0, stream>>>(y4, g4, b4, scsh4);

  // attention transpose (att_t aliases xt, which is now dead)
  attprep_kernel<<<256, 256, 0, stream>>>(atten, att_t);

  // local weighting + subtract, emits conv5 input in xt layout
  localw_kernel<<<dim3(64, 8), 256, 0, stream>>>(y1, scsh1, y4, scsh4, att_t, xt5);

  // conv5 path (output into y1 buffer)
  wprep_kernel<<<dim3(4, 2), 256, 0, stream>>>(w5, wpk, 128);
  convm_kernel<4><<<dim3(128, 4), 256, 0, stream>>>(xt5, wpk, y1);
  bnstats_kernel<<<128, 256, 0, stream>>>(y1, g5, b5, scsh5);

  pool_kernel<<<512, 256, 0, stream>>>(y1, scsh5, pooled);
  fc_kernel<<<1, 64, 0, stream>>>(pooled, fc1w, fc1b, fc2w, fc2b, out);
}

// Round 5
// 387.352 us; speedup vs baseline: 1.3383x; 1.3383x over previous
//
#include <hip/hip_runtime.h>
#include <hip/hip_bf16.h>

// KeySelect2 round 5: convm rebuilt with BOTH operands in LDS (m97 structure).
// Rounds 3-4 proved (VGPR=64) the allocator rematerializes global A-loads in
// the K-loop; LDS A-reads need no residency. Wave tile 64oc x 64pix -> 0.5
// ds_read per MFMA. Weights fragment-major in global -> linear DMA + linear
// conflict-free A ds_reads. K-split x4 + fp32 atomicAdd -> 2 blocks/CU.
// LDS: 48KB w double-buffer (3-tap steps) + 16KB x slab = exactly 64KB.

#define B_ 4
#define CM_ 128

typedef __attribute__((ext_vector_type(8))) short short8;
typedef __attribute__((ext_vector_type(4))) float floatx4;
typedef __attribute__((address_space(3))) unsigned lds_as;
typedef __attribute__((address_space(1))) const unsigned glb_as;

__device__ inline short f2bf(float f) {
  union { float f; unsigned u; } v; v.f = f;
  unsigned r = v.u + 0x7fff + ((v.u >> 16) & 1);  // RNE
  return (short)(r >> 16);
}
__device__ inline float bf2f(unsigned short u) {
  union { unsigned u; float f; } v; v.u = ((unsigned)u) << 16;
  return v.f;
}

// ---- x prepack: NCHW fp32 -> [b][kb][row][col][unit^sw][8] bf16 ------------
template <int KB>
__global__ void xprep_kernel(const float* __restrict__ x, short* __restrict__ xt) {
  int kb = blockIdx.x >> 4, rg = blockIdx.x & 15;
  int b = blockIdx.y;
  int row = rg * 4 + (threadIdx.x >> 6);
  int col = threadIdx.x & 63;
  const float* xs = x + (((size_t)b * (KB * 32) + kb * 32) * 64 + row) * 64 + col;
  short* xd = xt + ((((size_t)b * KB + kb) * 64 + row) * 64 + col) * 32;
  int sw = (col >> 1) & 3;
#pragma unroll
  for (int u = 0; u < 4; u++) {
    short8 pk;
#pragma unroll
    for (int j = 0; j < 8; j++) pk[j] = f2bf(xs[(size_t)(u * 8 + j) * 4096]);
    *(short8*)(xd + (u ^ sw) * 8) = pk;
  }
}

// ---- fused prep: xprep(low_key), wfrag 1/4/5, att transpose, zero y1+y4 ----
// wfrag layout: [kb][r(3)][s(3)][m(8)][lane(64)][8] shorts; lane=quad*16+n16
// holds oc=m*16+n16, ic=kb*32+quad*8+j  (= MFMA A-fragment order, lane-linear).
__global__ void prep1_kernel(const float* __restrict__ x1,
                             const float* __restrict__ w1, const float* __restrict__ w4,
                             const float* __restrict__ w5, const float* __restrict__ atten,
                             short* __restrict__ xt, short* __restrict__ wf1,
                             short* __restrict__ wf4, short* __restrict__ wf5,
                             float* __restrict__ att_t, float* __restrict__ yz) {
  __shared__ float tile[5184];
  int bx = blockIdx.x, tid = threadIdx.x;
  if (bx < 2048) {  // xprep for low_key
    int b = bx & 3, t = bx >> 2;
    int kb = t >> 4, rg = t & 15;
    int row = rg * 4 + (tid >> 6), col = tid & 63;
    const float* xs = x1 + (((size_t)b * 1024 + kb * 32) * 64 + row) * 64 + col;
    short* xd = xt + ((((size_t)b * 32 + kb) * 64 + row) * 64 + col) * 32;
    int sw = (col >> 1) & 3;
#pragma unroll
    for (int u = 0; u < 4; u++) {
      short8 pk;
#pragma unroll
      for (int j = 0; j < 8; j++) pk[j] = f2bf(xs[(size_t)(u * 8 + j) * 4096]);
      *(short8*)(xd + (u ^ sw) * 8) = pk;
    }
    return;
  }
  bx -= 2048;
  if (bx < 1024) {  // wf1 / wf4 (cin=1024)
    const float* w = bx < 512 ? w1 : w4;
    short* wf = bx < 512 ? wf1 : wf4;
    int idx = (bx & 511) * 256 + tid;
    int oc = idx >> 10, ic = idx & 1023;
    int kb = ic >> 5, icb = ic & 31, quad = icb >> 3, j = icb & 7;
    int m = oc >> 4, n16 = oc & 15, lane = quad * 16 + n16;
    const float* wp = w + ((size_t)oc * 1024 + ic) * 9;
    short* base = wf + (size_t)kb * 36864 + lane * 8 + j;
#pragma unroll
    for (int r = 0; r < 3; r++)
#pragma unroll
      for (int s = 0; s < 3; s++)
        base[(size_t)r * 12288 + (s * 8 + m) * 512] = f2bf(wp[r * 3 + s]);
    return;
  }
  bx -= 1024;
  if (bx < 64) {  // wf5 (cin=128)
    int idx = bx * 256 + tid;
    int oc = idx >> 7, ic = idx & 127;
    int kb = ic >> 5, icb = ic & 31, quad = icb >> 3, j = icb & 7;
    int m = oc >> 4, n16 = oc & 15, lane = quad * 16 + n16;
    const float* wp = w5 + ((size_t)oc * 128 + ic) * 9;
    short* base = wf5 + (size_t)kb * 36864 + lane * 8 + j;
#pragma unroll
    for (int r = 0; r < 3; r++)
#pragma unroll
      for (int s = 0; s < 3; s++)
        base[(size_t)r * 12288 + (s * 8 + m) * 512] = f2bf(wp[r * 3 + s]);
    return;
  }
  bx -= 64;
  if (bx < 256) {  // atten [b,pix,81] -> att_t [b,81,pix]
    int b = bx >> 6;
    int p0 = (bx & 63) * 64;
    const float* src = atten + ((size_t)b * 4096 + p0) * 81;
    for (int e = tid; e < 5184; e += 256) tile[e] = src[e];
    __syncthreads();
    for (int f = tid; f < 5184; f += 256) {
      int k = f >> 6, w_ = f & 63;
      att_t[((size_t)b * 81 + k) * 4096 + p0 + w_] = tile[w_ * 81 + k];
    }
    return;
  }
  bx -= 256;
  // zero y1+y4 (16,777,216 B): 4096 blocks x 256 threads x 16 B
  ((float4*)yz)[(size_t)bx * 256 + tid] = make_float4(0.f, 0.f, 0.f, 0.f);
}

// ---- MFMA conv, both operands in LDS ---------------------------------------
// grid (128, KSPLIT); block 256 (4 waves). Block tile 128 oc x 128 pix (2 rows).
// wave (mh=wv&1, nh=wv>>1): 64 ocs x one row. Per step (kb,r): 3 taps x
// (4 A + 4 B ds_read_b128, 16 MFMA) = 24 reads : 48 MFMA.
template <int KQ, bool ATOMIC>
__global__ __launch_bounds__(256, 2)
void convm_kernel(const short* __restrict__ xt, const short* __restrict__ wf,
                  float* __restrict__ ya, float* __restrict__ yb, int KBtot) {
  __shared__ __attribute__((aligned(16))) short smem[32768];  // 64 KB exactly
  // smem[0..24575]   : w double buffer, 2 x 12288 shorts ([s3][m8][lane64][8])
  // smem[24576..]    : x slab, 4 slots x 64 cols x 32 ic
  int tid = threadIdx.x, lane = tid & 63, wv = tid >> 6;
  int n16 = lane & 15, quad = lane >> 4;
  int pg = blockIdx.x;
  int b = pg >> 5, h0 = (pg & 31) * 2;
  int kb0 = blockIdx.y * KQ;
  int mh = wv & 1, nh = wv >> 1;
  float* yo = ATOMIC ? ya : (blockIdx.y ? yb : ya);
  short* sx = smem + 24576;

  // pre-zero boundary x slots (never DMA'd; x slab single-buffered, persists)
  if (h0 == 0)
    for (int i = tid; i < 1024; i += 256) ((int*)sx)[i] = 0;
  if (h0 == 62)
    for (int i = tid; i < 1024; i += 256) ((int*)(sx + 3 * 2048))[i] = 0;

  auto dma_x = [&](int kb) {
    int row = h0 - 1 + wv;  // wave wv stages slot wv
    if (row >= 0 && row < 64) {
      const short* src = xt + ((((size_t)b * KBtot + kb) * 64 + row) * 64) * 32 + lane * 8;
      short* dst = sx + wv * 2048 + lane * 8;
#pragma unroll
      for (int t = 0; t < 4; t++)
        __builtin_amdgcn_global_load_lds((glb_as*)(src + t * 512), (lds_as*)(dst + t * 512),
                                         16, 0, 0);
    }
  };
  auto dma_w = [&](int step, int buf) {  // step in [0, KQ*3)
    const short* src = wf + ((size_t)kb0 * 3 + step) * 12288 + wv * 3072 + lane * 8;
    short* dst = smem + buf * 12288 + wv * 3072 + lane * 8;
#pragma unroll
    for (int t = 0; t < 6; t++)
      __builtin_amdgcn_global_load_lds((glb_as*)(src + t * 512), (lds_as*)(dst + t * 512),
                                       16, 0, 0);
  };

  floatx4 acc[4][4];
#pragma unroll
  for (int i = 0; i < 4; i++)
#pragma unroll
    for (int n = 0; n < 4; n++) acc[i][n] = (floatx4){0.f, 0.f, 0.f, 0.f};

  dma_x(kb0);
  dma_w(0, 0);
  const int NS = KQ * 3;
  for (int s = 0; s < NS; s++) {
    int r = s % 3;
    __syncthreads();  // drains prior compute reads + outstanding DMA (vmcnt0)
    if (r == 0 && s > 0) {
      dma_x(kb0 + s / 3);  // x slab reads for prev kb completed at barrier
      if (s + 1 < NS) dma_w(s + 1, (s + 1) & 1);
      __syncthreads();  // drain the x DMA we just issued (exposed; 2 blk/CU overlap)
    } else {
      if (s + 1 < NS) dma_w(s + 1, (s + 1) & 1);
    }
    const short* swb = smem + (s & 1) * 12288;
    int slot = nh + r;  // in-row = h0+nh+(r-1) -> slot 0..3
    const short* sxr = sx + slot * 2048;
#pragma unroll
    for (int sp = 0; sp < 3; sp++) {
      short8 a[4];
#pragma unroll
      for (int i = 0; i < 4; i++)
        a[i] = *(const short8*)(swb + ((sp * 8 + mh * 4 + i) * 64 + lane) * 8);
#pragma unroll
      for (int n = 0; n < 4; n++) {
        int c = n * 16 + n16 + sp - 1;  // source col, -1..64
        int cc = c < 0 ? 0 : (c > 63 ? 63 : c);
        short8 bf = *(const short8*)(sxr + cc * 32 + (quad ^ ((cc >> 1) & 3)) * 8);
        if ((n == 0 && sp == 0) || (n == 3 && sp == 2)) {
          short8 zz = {0, 0, 0, 0, 0, 0, 0, 0};
          bf = (c != cc) ? zz : bf;  // zero out-of-image column lanes
        }
#pragma unroll
        for (int i = 0; i < 4; i++)
          acc[i][n] = __builtin_amdgcn_mfma_f32_16x16x32_bf16(a[i], bf, acc[i][n], 0, 0, 0);
      }
    }
  }

  int row = h0 + nh;
#pragma unroll
  for (int i = 0; i < 4; i++)
#pragma unroll
    for (int n = 0; n < 4; n++)
#pragma unroll
      for (int rg = 0; rg < 4; rg++) {
        int oc = mh * 64 + i * 16 + quad * 4 + rg;  // D: row=quad*4+reg, col=n16
        size_t gi = (((size_t)b * CM_ + oc) * 64 + row) * 64 + n * 16 + n16;
        if (ATOMIC)
          atomicAdd(&yo[gi], acc[i][n][rg]);
        else
          yo[gi] = acc[i][n][rg];
      }
}

// ---- BN stats (pair: by=0 -> set1, by=1 -> set4) ---------------------------
__global__ void bnstats2_kernel(const float* __restrict__ y1, const float* __restrict__ g1,
                                const float* __restrict__ b1, float2* __restrict__ s1,
                                const float* __restrict__ y4, const float* __restrict__ g4,
                                const float* __restrict__ b4, float2* __restrict__ s4) {
  const float* y = blockIdx.y ? y4 : y1;
  const float* g = blockIdx.y ? g4 : g1;
  const float* bt = blockIdx.y ? b4 : b1;
  float2* scsh = blockIdx.y ? s4 : s1;
  int c = blockIdx.x;
  int tid = threadIdx.x;
  float s = 0.f, s2 = 0.f;
  for (int b = 0; b < B_; b++) {
    const float4* p = (const float4*)(y + ((size_t)(b * CM_) + c) * 4096);
    for (int i = tid; i < 1024; i += 256) {
      float4 v = p[i];
      s += v.x + v.y + v.z + v.w;
      s2 += v.x * v.x + v.y * v.y + v.z * v.z + v.w * v.w;
    }
  }
  for (int off = 32; off > 0; off >>= 1) {
    s += __shfl_down(s, off);
    s2 += __shfl_down(s2, off);
  }
  __shared__ float rs[4], rq[4];
  if ((tid & 63) == 0) { rs[tid >> 6] = s; rq[tid >> 6] = s2; }
  __syncthreads();
  if (tid == 0) {
    float S = rs[0] + rs[1] + rs[2] + rs[3];
    float Q = rq[0] + rq[1] + rq[2] + rq[3];
    float mean = S * (1.f / 16384.f);
    float var = Q * (1.f / 16384.f) - mean * mean;
    float sc = g[c] * rsqrtf(var + 1e-5f);
    scsh[c] = make_float2(sc, bt[c] - mean * sc);
  }
}

// ---- BN stats over sum of two partial buffers ------------------------------
__global__ void bnstats_s2_kernel(const float* __restrict__ ya, const float* __restrict__ yb,
                                  const float* __restrict__ g, const float* __restrict__ bt,
                                  float2* __restrict__ scsh) {
  int c = blockIdx.x;
  int tid = threadIdx.x;
  float s = 0.f, s2 = 0.f;
  for (int b = 0; b < B_; b++) {
    const float4* p = (const float4*)(ya + ((size_t)(b * CM_) + c) * 4096);
    const float4* q = (const float4*)(yb + ((size_t)(b * CM_) + c) * 4096);
    for (int i = tid; i < 1024; i += 256) {
      float4 v = p[i], w = q[i];
      float a0 = v.x + w.x, a1 = v.y + w.y, a2 = v.z + w.z, a3 = v.w + w.w;
      s += a0 + a1 + a2 + a3;
      s2 += a0 * a0 + a1 * a1 + a2 * a2 + a3 * a3;
    }
  }
  for (int off = 32; off > 0; off >>= 1) {
    s += __shfl_down(s, off);
    s2 += __shfl_down(s2, off);
  }
  __shared__ float rs[4], rq[4];
  if ((tid & 63) == 0) { rs[tid >> 6] = s; rq[tid >> 6] = s2; }
  __syncthreads();
  if (tid == 0) {
    float S = rs[0] + rs[1] + rs[2] + rs[3];
    float Q = rq[0] + rq[1] + rq[2] + rq[3];
    float mean = S * (1.f / 16384.f);
    float var = Q * (1.f / 16384.f) - mean * mean;
    float sc = g[c] * rsqrtf(var + 1e-5f);
    scsh[c] = make_float2(sc, bt[c] - mean * sc);
  }
}

// ---- local weighting + subtract -> xt5 (bf16, conv5 layout) ----------------
__global__ __launch_bounds__(256, 2)
void localw_kernel(const float* __restrict__ y1, const float2* __restrict__ scsh1,
                   const float* __restrict__ y4, const float2* __restrict__ scsh4,
                   const float* __restrict__ att_t, short* __restrict__ xt5) {
  __shared__ unsigned short lkb[16][12][72];
  int bx = blockIdx.x;
  int b = bx >> 4, h0 = (bx & 15) * 4;
  int cg = blockIdx.y;
  int tid = threadIdx.x;
  int lane = tid & 63;
  int wv = tid >> 6;

  for (int e = tid; e < 16 * 12 * 72; e += 256) {
    int c_l = e / (12 * 72);
    int rem = e % (12 * 72);
    int gri = rem / 72, j = rem % 72;
    int row = h0 - 4 + gri, col = j - 4;
    float v = 0.f;
    if (row >= 0 && row < 64 && col >= 0 && col < 64) {
      float2 ss = scsh1[cg * 16 + c_l];
      v = fmaxf(0.f, y1[((size_t)(b * CM_) + cg * 16 + c_l) * 4096 + row * 64 + col] * ss.x + ss.y);
    }
    lkb[c_l][gri][j] = (unsigned short)f2bf(v);
  }
  __syncthreads();

  float acc[4][4];
#pragma unroll
  for (int cc = 0; cc < 4; cc++)
#pragma unroll
    for (int h_i = 0; h_i < 4; h_i++) acc[cc][h_i] = 0.f;

  const float* ab = att_t + (size_t)b * 81 * 4096 + h0 * 64 + lane;

#pragma unroll
  for (int gri = 0; gri < 12; ++gri) {
    float win[4][9];
#pragma unroll
    for (int cc = 0; cc < 4; ++cc)
#pragma unroll
      for (int dw = 0; dw < 9; ++dw)
        win[cc][dw] = bf2f(lkb[wv * 4 + cc][gri][lane + dw]);
#pragma unroll
    for (int h_i = 0; h_i < 4; ++h_i) {
      int r = gri - h_i;
      if (r < 0 || r > 8) continue;
      const float* ap = ab + (size_t)(r * 9) * 4096 + h_i * 64;
      float a[9];
#pragma unroll
      for (int dw = 0; dw < 9; ++dw) a[dw] = ap[(size_t)dw * 4096];
#pragma unroll
      for (int cc = 0; cc < 4; ++cc)
#pragma unroll
        for (int dw = 0; dw < 9; ++dw)
          acc[cc][h_i] = fmaf(a[dw], win[cc][dw], acc[cc][h_i]);
    }
  }

#pragma unroll
  for (int cc = 0; cc < 4; ++cc) {
    int c = cg * 16 + wv * 4 + cc;
    float2 ss4 = scsh4[c];
    int icb = c & 31;
    int uu = (icb >> 3) ^ ((lane >> 1) & 3);
#pragma unroll
    for (int h_i = 0; h_i < 4; ++h_i) {
      int h = h0 + h_i;
      size_t gi = ((size_t)(b * CM_) + c) * 4096 + h * 64 + lane;
      float lnk = fmaxf(0.f, y4[gi] * ss4.x + ss4.y);
      float dv = acc[cc][h_i] - lnk;
      xt5[((((size_t)b * 4 + (c >> 5)) * 64 + h) * 64 + lane) * 32 + uu * 8 + (icb & 7)] =
          f2bf(dv);
    }
  }
}

// ---- global avg pool with BN+ReLU over two partials ------------------------
__global__ void pool_kernel(const float* __restrict__ ya, const float* __restrict__ yb,
                            const float2* __restrict__ scsh, float* __restrict__ pooled) {
  int bc = blockIdx.x;
  int c = bc & 127;
  float2 ss = scsh[c];
  const float4* p = (const float4*)(ya + (size_t)bc * 4096);
  const float4* q = (const float4*)(yb + (size_t)bc * 4096);
  float s = 0.f;
  for (int i = threadIdx.x; i < 1024; i += 256) {
    float4 v = p[i], w = q[i];
    s += fmaxf(0.f, (v.x + w.x) * ss.x + ss.y) + fmaxf(0.f, (v.y + w.y) * ss.x + ss.y) +
         fmaxf(0.f, (v.z + w.z) * ss.x + ss.y) + fmaxf(0.f, (v.w + w.w) * ss.x + ss.y);
  }
  for (int off = 32; off > 0; off >>= 1) s += __shfl_down(s, off);
  __shared__ float rs[4];
  if ((threadIdx.x & 63) == 0) rs[threadIdx.x >> 6] = s;
  __syncthreads();
  if (threadIdx.x == 0) pooled[bc] = (rs[0] + rs[1] + rs[2] + rs[3]) * (1.f / 4096.f);
}

// ---- fc1 + fc2 -------------------------------------------------------------
__global__ void fc_kernel(const float* __restrict__ pooled, const float* __restrict__ fc1w,
                          const float* __restrict__ fc1b, const float* __restrict__ fc2w,
                          const float* __restrict__ fc2b, float* __restrict__ out) {
  int lane = threadIdx.x;
  float p[B_][10];
#pragma unroll
  for (int b = 0; b < B_; b++)
#pragma unroll
    for (int j = 0; j < 10; j++) p[b][j] = 0.f;
  for (int c = lane; c < CM_; c += 64) {
#pragma unroll
    for (int b = 0; b < B_; b++) {
      float pv = pooled[b * CM_ + c];
#pragma unroll
      for (int j = 0; j < 10; j++) p[b][j] = fmaf(pv, fc1w[j * CM_ + c], p[b][j]);
    }
  }
  for (int off = 32; off > 0; off >>= 1)
#pragma unroll
    for (int b = 0; b < B_; b++)
#pragma unroll
      for (int j = 0; j < 10; j++) p[b][j] += __shfl_down(p[b][j], off);
  if (lane == 0) {
    for (int b = 0; b < B_; b++) {
      float o = fc2b[0];
      for (int j = 0; j < 10; j++) o += fc2w[j] * (p[b][j] + fc1b[j]);
      out[b] = o;
    }
  }
}

extern "C" void kernel_launch(void* const* d_in, const int* in_sizes, int n_in,
                              void* d_out, int out_size, void* d_ws, size_t ws_size,
                              hipStream_t stream) {
  const float* low_key    = (const float*)d_in[0];
  const float* low_nonkey = (const float*)d_in[1];
  const float* atten      = (const float*)d_in[2];
  const float* w1  = (const float*)d_in[3];
  const float* g1  = (const float*)d_in[4];
  const float* b1  = (const float*)d_in[5];
  const float* w4  = (const float*)d_in[6];
  const float* g4  = (const float*)d_in[7];
  const float* b4  = (const float*)d_in[8];
  const float* w5  = (const float*)d_in[9];
  const float* g5  = (const float*)d_in[10];
  const float* b5  = (const float*)d_in[11];
  const float* fc1w = (const float*)d_in[12];
  const float* fc1b = (const float*)d_in[13];
  const float* fc2w = (const float*)d_in[14];
  const float* fc2b = (const float*)d_in[15];

  char* w8 = (char*)d_ws;
  short* wf1   = (short*)w8;                       // 2,359,296 B
  short* wf4   = (short*)(w8 + 2359296);           // 2,359,296 B
  short* wf5   = (short*)(w8 + 4718592);           //   294,912 B (pad to 589,824)
  float* att_t = (float*)(w8 + 5308416);           // 5,308,416 B
  short* xt    = (short*)(w8 + 10616832);          // 33,554,432 B (xt5 aliases base)
  float* y1    = (float*)(w8 + 44171264);          // 8,388,608 B (zeroed; conv1 acc; y5a)
  float* y4    = (float*)(w8 + 52559872);          // 8,388,608 B (zeroed; conv4 acc; y5b)
  float2* scsh1 = (float2*)(w8 + 60948480);
  float2* scsh4 = scsh1 + CM_;
  float2* scsh5 = scsh4 + CM_;
  float* pooled = (float*)(scsh5 + CM_);
  short* xt5 = xt;  // conv5 input, written by localw after xt is dead
  float* out = (float*)d_out;

  // 1. fused prep: xt(low_key), wf1/wf4/wf5 fragment-major, att_t, zero y1+y4
  prep1_kernel<<<7488, 256, 0, stream>>>(low_key, w1, w4, w5, atten,
                                         xt, wf1, wf4, wf5, att_t, y1);
  // 2. conv1: K-split x4, atomic accumulate into zeroed y1
  convm_kernel<8, true><<<dim3(128, 4), 256, 0, stream>>>(xt, wf1, y1, y1, 32);
  // 3. xprep for low_nonkey (reuses xt)
  xprep_kernel<32><<<dim3(512, 4), 256, 0, stream>>>(low_nonkey, xt);
  // 4. conv4
  convm_kernel<8, true><<<dim3(128, 4), 256, 0, stream>>>(xt, wf4, y4, y4, 32);
  // 5. BN stats for conv1 & conv4 in one launch
  bnstats2_kernel<<<dim3(128, 2), 256, 0, stream>>>(y1, g1, b1, scsh1, y4, g4, b4, scsh4);
  // 6. local weighting + subtract -> xt5 (bf16 conv5 layout)
  localw_kernel<<<dim3(64, 8), 256, 0, stream>>>(y1, scsh1, y4, scsh4, att_t, xt5);
  // 7. conv5: K-split x2, non-atomic partials into now-dead y1/y4 regions
  convm_kernel<2, false><<<dim3(128, 2), 256, 0, stream>>>(xt5, wf5, y1, y4, 4);
  // 8. BN stats over y5 = y1+y4 partials
  bnstats_s2_kernel<<<128, 256, 0, stream>>>(y1, y4, g5, b5, scsh5);
  // 9. pool + 10. fc
  pool_kernel<<<512, 256, 0, stream>>>(y1, y4, scsh5, pooled);
  fc_kernel<<<1, 64, 0, stream>>>(pooled, fc1w, fc1b, fc2w, fc2b, out);
}